// Round 2
// baseline (9123.804 us; speedup 1.0000x reference)
//
#include <hip/hip_runtime.h>
#include <hip/hip_bf16.h>

// V=10000, R=8192, D=1024, B=1024, L=64, M=65536
#define D_DIM   1024
#define L_SEQ   64
#define B_BATCH 1024
#define M_NODES 65536
#define R_RULES 8192

// fp32 tiled GEMM config: 64x64 tile, BK=16, 256 threads, 4x4 per thread.
#define BM 64
#define BN 64
#define BK 16
#define LDP (BM + 4)

typedef unsigned short bf16_t;

static __device__ __forceinline__ float bf2f(bf16_t u) {
    union { unsigned int i; float f; } v; v.i = ((unsigned int)u) << 16; return v.f;
}
static __device__ __forceinline__ bf16_t f2bf(float f) {  // round-to-nearest-even
    union { float f; unsigned int i; } v; v.f = f;
    return (bf16_t)((v.i + 0x7FFFu + ((v.i >> 16) & 1u)) >> 16);
}

// ---------------------------------------------------------------------------
// Kernel 1: XE[n,:] = bf16(emb[tokens[n],:] @ Wxh + bh)     n in [0, B*L)
// ---------------------------------------------------------------------------
__global__ __launch_bounds__(256) void k_xw(
    const int* __restrict__ tokens, const float* __restrict__ emb,
    const float* __restrict__ Wxh, const float* __restrict__ bh,
    bf16_t* __restrict__ XE)
{
    __shared__ float As[BK][LDP];
    __shared__ float Bs[BK][LDP];
    const int tid  = threadIdx.x;
    const int row0 = blockIdx.x * BM;
    const int col0 = blockIdx.y * BN;
    const int ar = tid >> 2,  ak = (tid & 3) << 2;   // A loader: row, k4
    const int bk = tid >> 4,  bn = (tid & 15) << 2;  // B loader: k, col4
    const int tx = tid & 15,  ty = tid >> 4;

    const int tok = tokens[row0 + ar];
    const float* aptr = emb + (size_t)tok * D_DIM + ak;
    const float* bptr = Wxh + (size_t)bk * D_DIM + col0 + bn;

    float acc[4][4] = {};
    for (int k0 = 0; k0 < D_DIM; k0 += BK) {
        float4 av = *(const float4*)(aptr + k0);
        As[ak + 0][ar] = av.x; As[ak + 1][ar] = av.y;
        As[ak + 2][ar] = av.z; As[ak + 3][ar] = av.w;
        *(float4*)&Bs[bk][bn] = *(const float4*)(bptr + (size_t)k0 * D_DIM);
        __syncthreads();
#pragma unroll
        for (int kk = 0; kk < BK; ++kk) {
            float4 a = *(float4*)&As[kk][ty * 4];
            float4 b = *(float4*)&Bs[kk][tx * 4];
            float aa[4] = {a.x, a.y, a.z, a.w};
            float bb[4] = {b.x, b.y, b.z, b.w};
#pragma unroll
            for (int i = 0; i < 4; ++i)
#pragma unroll
                for (int j = 0; j < 4; ++j)
                    acc[i][j] += aa[i] * bb[j];
        }
        __syncthreads();
    }
    float4 bias = *(const float4*)&bh[col0 + tx * 4];
#pragma unroll
    for (int i = 0; i < 4; ++i) {
        int r = row0 + ty * 4 + i;
        ushort4 st;
        st.x = f2bf(acc[i][0] + bias.x); st.y = f2bf(acc[i][1] + bias.y);
        st.z = f2bf(acc[i][2] + bias.z); st.w = f2bf(acc[i][3] + bias.w);
        *(ushort4*)&XE[(size_t)r * D_DIM + col0 + tx * 4] = st;
    }
}

// ---------------------------------------------------------------------------
// Kernel 2 (x64, sequential):
//   y = tanh(XE[b*L+t,:] + H_prev[b,:]@Whh);  h_new[b,:]=y (fp32);  XE[b*L+t,:]=bf16(y)
// H_prev read from Abase + b*strideA (strideA=0 broadcasts h0 at t=0).
// ---------------------------------------------------------------------------
__global__ __launch_bounds__(256) void k_step(
    const float* __restrict__ Abase, int strideA,
    const float* __restrict__ Whh,
    bf16_t* __restrict__ XE, float* __restrict__ h_new, int t)
{
    __shared__ float As[BK][LDP];
    __shared__ float Bs[BK][LDP];
    const int tid  = threadIdx.x;
    const int row0 = blockIdx.x * BM;   // b tile
    const int col0 = blockIdx.y * BN;
    const int ar = tid >> 2,  ak = (tid & 3) << 2;
    const int bk = tid >> 4,  bn = (tid & 15) << 2;
    const int tx = tid & 15,  ty = tid >> 4;

    const float* aptr = Abase + (size_t)(row0 + ar) * strideA + ak;
    const float* bptr = Whh + (size_t)bk * D_DIM + col0 + bn;

    float acc[4][4] = {};
    for (int k0 = 0; k0 < D_DIM; k0 += BK) {
        float4 av = *(const float4*)(aptr + k0);
        As[ak + 0][ar] = av.x; As[ak + 1][ar] = av.y;
        As[ak + 2][ar] = av.z; As[ak + 3][ar] = av.w;
        *(float4*)&Bs[bk][bn] = *(const float4*)(bptr + (size_t)k0 * D_DIM);
        __syncthreads();
#pragma unroll
        for (int kk = 0; kk < BK; ++kk) {
            float4 a = *(float4*)&As[kk][ty * 4];
            float4 b = *(float4*)&Bs[kk][tx * 4];
            float aa[4] = {a.x, a.y, a.z, a.w};
            float bb[4] = {b.x, b.y, b.z, b.w};
#pragma unroll
            for (int i = 0; i < 4; ++i)
#pragma unroll
                for (int j = 0; j < 4; ++j)
                    acc[i][j] += aa[i] * bb[j];
        }
        __syncthreads();
    }
#pragma unroll
    for (int i = 0; i < 4; ++i) {
        int b = row0 + ty * 4 + i;
        size_t idx = (size_t)((b << 6) + t) * D_DIM + col0 + tx * 4;  // (b*L+t)*D
        ushort4 xr = *(const ushort4*)&XE[idx];
        float y0 = tanhf(bf2f(xr.x) + acc[i][0]);
        float y1 = tanhf(bf2f(xr.y) + acc[i][1]);
        float y2 = tanhf(bf2f(xr.z) + acc[i][2]);
        float y3 = tanhf(bf2f(xr.w) + acc[i][3]);
        float4 hv; hv.x = y0; hv.y = y1; hv.z = y2; hv.w = y3;
        *(float4*)&h_new[(size_t)b * D_DIM + col0 + tx * 4] = hv;
        ushort4 st; st.x = f2bf(y0); st.y = f2bf(y1); st.z = f2bf(y2); st.w = f2bf(y3);
        *(ushort4*)&XE[idx] = st;
    }
}

// ---------------------------------------------------------------------------
// Kernel 3: h = tanh(concat(enc[i_idx[m]], enc[j_idx[m]]) @ W1 + b1), then fused
// partial rule-dot: partials[cb, m] = dot(h[m, col0:col0+64], W2T[r_idx[m], col0:col0+64])
// ---------------------------------------------------------------------------
__global__ __launch_bounds__(256) void k_mlp_score(
    const int* __restrict__ i_idx, const int* __restrict__ j_idx,
    const bf16_t* __restrict__ XE,
    const float* __restrict__ W1, const float* __restrict__ b1,
    const float* __restrict__ Wt2, const int* __restrict__ r_idx,
    float* __restrict__ partials)
{
    __shared__ float As[BK][LDP];
    __shared__ float Bs[BK][LDP];
    const int tid  = threadIdx.x;
    const int row0 = blockIdx.x * BM;
    const int col0 = blockIdx.y * BN;
    const int ar = tid >> 2,  ak = (tid & 3) << 2;
    const int bk = tid >> 4,  bn = (tid & 15) << 2;
    const int tx = tid & 15,  ty = tid >> 4;

    const int m  = row0 + ar;
    const bf16_t* plo = XE + (size_t)i_idx[m] * D_DIM;           // k in [0,1024)
    const bf16_t* phi = XE + (size_t)j_idx[m] * D_DIM - D_DIM;   // k in [1024,2048)
    const float* bptr = W1 + (size_t)bk * D_DIM + col0 + bn;

    float acc[4][4] = {};
    for (int k0 = 0; k0 < 2 * D_DIM; k0 += BK) {
        const bf16_t* p = (k0 + ak < D_DIM) ? plo : phi;
        ushort4 raw = *(const ushort4*)(p + k0 + ak);
        As[ak + 0][ar] = bf2f(raw.x); As[ak + 1][ar] = bf2f(raw.y);
        As[ak + 2][ar] = bf2f(raw.z); As[ak + 3][ar] = bf2f(raw.w);
        *(float4*)&Bs[bk][bn] = *(const float4*)(bptr + (size_t)k0 * D_DIM);
        __syncthreads();
#pragma unroll
        for (int kk = 0; kk < BK; ++kk) {
            float4 a = *(float4*)&As[kk][ty * 4];
            float4 b = *(float4*)&Bs[kk][tx * 4];
            float aa[4] = {a.x, a.y, a.z, a.w};
            float bb[4] = {b.x, b.y, b.z, b.w};
#pragma unroll
            for (int i = 0; i < 4; ++i)
#pragma unroll
                for (int j = 0; j < 4; ++j)
                    acc[i][j] += aa[i] * bb[j];
        }
        __syncthreads();
    }
    float4 bias = *(const float4*)&b1[col0 + tx * 4];
#pragma unroll
    for (int i = 0; i < 4; ++i) {
        int mi = row0 + ty * 4 + i;
        float h0v = tanhf(acc[i][0] + bias.x);
        float h1v = tanhf(acc[i][1] + bias.y);
        float h2v = tanhf(acc[i][2] + bias.z);
        float h3v = tanhf(acc[i][3] + bias.w);
        int r = r_idx[mi];
        float4 w = *(const float4*)&Wt2[(size_t)r * D_DIM + col0 + tx * 4];
        float s = h0v * w.x + h1v * w.y + h2v * w.z + h3v * w.w;
        // reduce across the 16-lane row group (lanes tid = ty*16 + tx, contiguous)
        s += __shfl_xor(s, 1);
        s += __shfl_xor(s, 2);
        s += __shfl_xor(s, 4);
        s += __shfl_xor(s, 8);
        if (tx == 0)
            partials[(size_t)blockIdx.y * M_NODES + mi] = s;
    }
}

// ---------------------------------------------------------------------------
// Kernel 0: W2T[r,d] = W2[d,r]
// ---------------------------------------------------------------------------
__global__ __launch_bounds__(256) void k_transpose(
    const float* __restrict__ W2, float* __restrict__ W2T)
{
    __shared__ float s[32][33];
    int c0 = blockIdx.x * 32;  // R dim
    int r0 = blockIdx.y * 32;  // D dim
#pragma unroll
    for (int i = 0; i < 4; ++i) {
        int r = r0 + threadIdx.y + i * 8;
        s[threadIdx.y + i * 8][threadIdx.x] = W2[(size_t)r * R_RULES + c0 + threadIdx.x];
    }
    __syncthreads();
#pragma unroll
    for (int i = 0; i < 4; ++i) {
        int c = c0 + threadIdx.y + i * 8;
        W2T[(size_t)c * D_DIM + r0 + threadIdx.x] = s[threadIdx.x][threadIdx.y + i * 8];
    }
}

// ---------------------------------------------------------------------------
// Kernel 4: out[m] = sum_cb partials[cb, m] + b2[r_idx[m]]   (deterministic)
// ---------------------------------------------------------------------------
__global__ __launch_bounds__(256) void k_reduce(
    const float* __restrict__ partials, const int* __restrict__ r_idx,
    const float* __restrict__ b2, float* __restrict__ out)
{
    int m = blockIdx.x * 256 + threadIdx.x;
    float s = 0.f;
#pragma unroll
    for (int cb = 0; cb < 16; ++cb)
        s += partials[(size_t)cb * M_NODES + m];
    out[m] = s + b2[r_idx[m]];
}

// ---------------------------------------------------------------------------
extern "C" void kernel_launch(void* const* d_in, const int* in_sizes, int n_in,
                              void* d_out, int out_size, void* d_ws, size_t ws_size,
                              hipStream_t stream) {
    const int*   tokens = (const int*)  d_in[0];   // [B, L]
    const int*   i_idx  = (const int*)  d_in[1];   // [M]
    const int*   j_idx  = (const int*)  d_in[2];   // [M]
    const int*   r_idx  = (const int*)  d_in[3];   // [M]
    const float* emb    = (const float*)d_in[4];   // [V, D]
    const float* Wxh    = (const float*)d_in[5];   // [D, D]
    const float* Whh    = (const float*)d_in[6];   // [D, D]
    const float* bh     = (const float*)d_in[7];   // [D]
    const float* h0     = (const float*)d_in[8];   // [D]
    const float* W1     = (const float*)d_in[9];   // [2D, D]
    const float* b1     = (const float*)d_in[10];  // [D]
    const float* W2     = (const float*)d_in[11];  // [D, R]
    const float* b2     = (const float*)d_in[12];  // [R]
    float* out = (float*)d_out;                    // [M]

    // Workspace layout — total 172 MiB (was 544 MiB; suspected cause of the R1 fault):
    //   XE   bf16 [B*L, D]   128 MiB  (Xw, overwritten in place by enc)
    //   Wt2  fp32 [R, D]      32 MiB
    //   hA/hB fp32 [B, D]    2x4 MiB  (fp32 recurrence ping-pong)
    //   partials fp32 [16, M]  4 MiB
    bf16_t* XE  = (bf16_t*)d_ws;
    float*  Wt2 = (float*)(XE + (size_t)M_NODES * D_DIM);
    float*  hA  = Wt2 + (size_t)R_RULES * D_DIM;
    float*  hB  = hA + (size_t)B_BATCH * D_DIM;
    float*  par = hB + (size_t)B_BATCH * D_DIM;

    // 0) W2T
    k_transpose<<<dim3(R_RULES / 32, D_DIM / 32), dim3(32, 8), 0, stream>>>(W2, Wt2);

    // 1) XE = bf16(emb[tokens] @ Wxh + bh)
    k_xw<<<dim3(M_NODES / BM, D_DIM / BN), 256, 0, stream>>>(tokens, emb, Wxh, bh, XE);

    // 2) RNN scan: 64 sequential GEMM+tanh steps (fp32 recurrence, bf16 enc store)
    for (int t = 0; t < L_SEQ; ++t) {
        const float* Aprev = (t == 0) ? h0 : ((t & 1) ? hA : hB);
        int strideA        = (t == 0) ? 0  : D_DIM;
        float* hNew        = (t & 1) ? hB : hA;
        k_step<<<dim3(B_BATCH / BM, D_DIM / BN), 256, 0, stream>>>(
            Aprev, strideA, Whh, XE, hNew, t);
    }

    // 3) MLP + fused partial rule-dot
    k_mlp_score<<<dim3(M_NODES / BM, D_DIM / BN), 256, 0, stream>>>(
        i_idx, j_idx, XE, W1, b1, Wt2, r_idx, par);

    // 4) deterministic reduction + b2
    k_reduce<<<M_NODES / 256, 256, 0, stream>>>(par, r_idx, b2, out);
}

// Round 6
// 1659.130 us; speedup vs baseline: 5.4992x; 5.4992x over previous
//
#include <hip/hip_runtime.h>

// V=10000, R=8192, D=1024, B=1024, L=64, M=65536
// R6 = R5 resubmitted verbatim. R3/R4 (async staging) and R5 (manual staging)
// all died with "MI355X container failed twice" — two disjoint kernel bodies,
// 6 container attempts. Static audit of R5 finds no hang path (uniform
// barriers, bounded loops, aligned accesses, in-bounds). Primary theory is
// persistent infra/node failure; resubmitting unchanged to test it. If this
// fails again, next round submits the known-good R2 kernel as the control.
#define D_DIM   1024
#define L_SEQ   64
#define B_BATCH 1024
#define M_NODES 65536
#define R_RULES 8192

typedef unsigned short bf16_t;
typedef __attribute__((ext_vector_type(8))) short s8v;   // 8 bf16 = 4 VGPR (MFMA A/B frag)
typedef __attribute__((ext_vector_type(4))) float f4v;   // MFMA C/D frag

static __device__ __forceinline__ float bf2f(unsigned short u) {
    union { unsigned int i; float f; } v; v.i = ((unsigned int)u) << 16; return v.f;
}
static __device__ __forceinline__ unsigned short f2bf(float f) {  // RNE
    union { float f; unsigned int i; } v; v.f = f;
    return (unsigned short)((v.i + 0x7FFFu + ((v.i >> 16) & 1u)) >> 16);
}

static __device__ __forceinline__ f4v mfma16(s8v a, s8v b, f4v c) {
    return __builtin_amdgcn_mfma_f32_16x16x32_bf16(a, b, c, 0, 0, 0);
}

// ---------------------------------------------------------------------------
// k_transcvt: dst[n][k] = bf16(src[k][n])   (weights -> B-operand layout)
// ---------------------------------------------------------------------------
__global__ __launch_bounds__(256) void k_transcvt(
    const float* __restrict__ src, bf16_t* __restrict__ dst, int K, int N)
{
    __shared__ float s[32][33];
    int n0 = blockIdx.x * 32, k0 = blockIdx.y * 32;
    int tx = threadIdx.x, ty = threadIdx.y;  // (32,8)
#pragma unroll
    for (int i = 0; i < 4; ++i)
        s[ty + i * 8][tx] = src[(size_t)(k0 + ty + i * 8) * N + n0 + tx];
    __syncthreads();
#pragma unroll
    for (int i = 0; i < 4; ++i)
        dst[(size_t)(n0 + ty + i * 8) * K + k0 + tx] = f2bf(s[tx][ty + i * 8]);
}

__global__ __launch_bounds__(256) void k_cvt_h0(
    const float* __restrict__ h0, bf16_t* __restrict__ h0b)
{
    for (int u = threadIdx.x; u < D_DIM; u += 256) h0b[u] = f2bf(h0[u]);
}

// ---------------------------------------------------------------------------
// k_xw_mfma: XE[n,:] = bf16(emb[tokens[n],:] @ Wxh + bh)
// 128x128 tile, BK=32, A = fp32 emb rows (gathered), B = WxhT bf16.
// Manual staging: global->VGPR->LDS.
// ---------------------------------------------------------------------------
__global__ __launch_bounds__(256) void k_xw_mfma(
    const int* __restrict__ tokens, const float* __restrict__ emb,
    const bf16_t* __restrict__ WxhT, const float* __restrict__ bh,
    bf16_t* __restrict__ XE)
{
    __shared__ float  As[128 * 32];            // 16 KB (fp32 A tile, [row][k] rows of 32)
    __shared__ bf16_t Bs[128 * 32];            // 8 KB  ([n][k] rows of 32)
    __shared__ float  epi[4][16][68];          // 17.4 KB

    const int tid = threadIdx.x;
    const int w = tid >> 6, l = tid & 63;
    const int q = l >> 4, t16 = l & 15;
    const int wm = (w >> 1) * 64, wn = (w & 1) * 64;
    const int row0 = blockIdx.x * 128, col0 = blockIdx.y * 128;

    // A loader: rows tid>>3 + r*32, 16B chunk (tid&7)*4 f32 within the 128B row
    const float* arow[4];
#pragma unroll
    for (int r = 0; r < 4; ++r)
        arow[r] = emb + (size_t)tokens[row0 + (tid >> 3) + r * 32] * D_DIM + ((tid & 7) << 2);
    // B loader: rows n = tid>>2 + r*64, chunk (tid&3)*8 bf16
    const bf16_t* brow[2];
#pragma unroll
    for (int r = 0; r < 2; ++r)
        brow[r] = WxhT + (size_t)(col0 + (tid >> 2) + r * 64) * D_DIM + ((tid & 3) << 3);

    f4v acc[4][4];
#pragma unroll
    for (int i = 0; i < 4; ++i)
#pragma unroll
        for (int j = 0; j < 4; ++j) acc[i][j] = (f4v)0.f;

    for (int k0 = 0; k0 < D_DIM; k0 += 32) {
        f4v aldg[4];
        s8v bldg[2];
#pragma unroll
        for (int r = 0; r < 4; ++r) aldg[r] = *(const f4v*)(arow[r] + k0);
#pragma unroll
        for (int r = 0; r < 2; ++r) bldg[r] = *(const s8v*)(brow[r] + k0);
        __syncthreads();   // previous iteration's consumers done
#pragma unroll
        for (int r = 0; r < 4; ++r) *(f4v*)&As[((tid >> 3) + r * 32) * 32 + ((tid & 7) << 2)] = aldg[r];
#pragma unroll
        for (int r = 0; r < 2; ++r) *(s8v*)&Bs[((tid >> 2) + r * 64) * 32 + ((tid & 3) << 3)] = bldg[r];
        __syncthreads();
        s8v af[4], bfr[4];
#pragma unroll
        for (int ti = 0; ti < 4; ++ti) {
            const float* pa = &As[(wm + ti * 16 + t16) * 32 + q * 8];
            f4v x0 = *(const f4v*)pa, x1 = *(const f4v*)(pa + 4);
            s8v a;
            a[0] = (short)f2bf(x0.x); a[1] = (short)f2bf(x0.y);
            a[2] = (short)f2bf(x0.z); a[3] = (short)f2bf(x0.w);
            a[4] = (short)f2bf(x1.x); a[5] = (short)f2bf(x1.y);
            a[6] = (short)f2bf(x1.z); a[7] = (short)f2bf(x1.w);
            af[ti] = a;
        }
#pragma unroll
        for (int tj = 0; tj < 4; ++tj)
            bfr[tj] = *(const s8v*)&Bs[(wn + tj * 16 + t16) * 32 + q * 8];
#pragma unroll
        for (int ti = 0; ti < 4; ++ti)
#pragma unroll
            for (int tj = 0; tj < 4; ++tj)
                acc[ti][tj] = mfma16(af[ti], bfr[tj], acc[ti][tj]);
    }

    // epilogue: +bias, bf16, LDS transpose -> coalesced 16B stores
    const int lr = l >> 2, c16 = (l & 3) * 16;
    f4v bias[4];
#pragma unroll
    for (int u = 0; u < 4; ++u)
        bias[u] = *(const f4v*)&bh[col0 + wn + c16 + u * 4];
#pragma unroll
    for (int ti = 0; ti < 4; ++ti) {
        __syncthreads();
#pragma unroll
        for (int tj = 0; tj < 4; ++tj)
#pragma unroll
            for (int rg = 0; rg < 4; ++rg)
                epi[w][q * 4 + rg][tj * 16 + t16] = acc[ti][tj][rg];
        __syncthreads();
        s8v o0, o1;
#pragma unroll
        for (int u = 0; u < 8; ++u) {
            o0[u] = (short)f2bf(epi[w][lr][c16 + u]     + bias[u >> 2][u & 3]);
            o1[u] = (short)f2bf(epi[w][lr][c16 + 8 + u] + bias[2 + (u >> 2)][u & 3]);
        }
        size_t orow = (size_t)(row0 + wm + ti * 16 + lr) * D_DIM + col0 + wn + c16;
        *(s8v*)&XE[orow]     = o0;
        *(s8v*)&XE[orow + 8] = o1;
    }
}

// ---------------------------------------------------------------------------
// k_step_mfma (x64): y = tanh(XE[b*L+t,:] + h_prev[b,:] @ Whh); XE[b*L+t,:] = bf16(y)
// 64x64 tile (256 blocks), A = bf16 h rows (XE stride 64*D, or h0 stride 0).
// ---------------------------------------------------------------------------
__global__ __launch_bounds__(256) void k_step_mfma(
    const bf16_t* __restrict__ Abase, int strideRow,
    const bf16_t* __restrict__ WhhT, bf16_t* __restrict__ XE, int t)
{
    __shared__ bf16_t As[64 * 32];             // 4 KB
    __shared__ bf16_t Bs[64 * 32];             // 4 KB
    __shared__ float  epi[4][16][36];          // 9.2 KB

    const int tid = threadIdx.x;
    const int w = tid >> 6, l = tid & 63;
    const int q = l >> 4, t16 = l & 15;
    const int wm = (w >> 1) * 32, wn = (w & 1) * 32;
    const int row0 = blockIdx.x * 64, col0 = blockIdx.y * 64;

    const bf16_t* asrc = Abase + (size_t)(row0 + (tid >> 2)) * strideRow + ((tid & 3) << 3);
    const bf16_t* bsrc = WhhT + (size_t)(col0 + (tid >> 2)) * D_DIM + ((tid & 3) << 3);

    f4v acc[2][2];
#pragma unroll
    for (int i = 0; i < 2; ++i)
#pragma unroll
        for (int j = 0; j < 2; ++j) acc[i][j] = (f4v)0.f;

    for (int k0 = 0; k0 < D_DIM; k0 += 32) {
        s8v av = *(const s8v*)(asrc + k0);
        s8v bv = *(const s8v*)(bsrc + k0);
        __syncthreads();
        *(s8v*)&As[((tid >> 2)) * 32 + ((tid & 3) << 3)] = av;
        *(s8v*)&Bs[((tid >> 2)) * 32 + ((tid & 3) << 3)] = bv;
        __syncthreads();
        s8v af[2], bfr[2];
#pragma unroll
        for (int ti = 0; ti < 2; ++ti)
            af[ti] = *(const s8v*)&As[(wm + ti * 16 + t16) * 32 + q * 8];
#pragma unroll
        for (int tj = 0; tj < 2; ++tj)
            bfr[tj] = *(const s8v*)&Bs[(wn + tj * 16 + t16) * 32 + q * 8];
#pragma unroll
        for (int ti = 0; ti < 2; ++ti)
#pragma unroll
            for (int tj = 0; tj < 2; ++tj)
                acc[ti][tj] = mfma16(af[ti], bfr[tj], acc[ti][tj]);
    }

    const int lr = l >> 2, c8 = (l & 3) * 8;
#pragma unroll
    for (int ti = 0; ti < 2; ++ti) {
        __syncthreads();
#pragma unroll
        for (int tj = 0; tj < 2; ++tj)
#pragma unroll
            for (int rg = 0; rg < 4; ++rg)
                epi[w][q * 4 + rg][tj * 16 + t16] = acc[ti][tj][rg];
        __syncthreads();
        f4v v0 = *(const f4v*)&epi[w][lr][c8];
        f4v v1 = *(const f4v*)&epi[w][lr][c8 + 4];
        int b = row0 + wm + ti * 16 + lr;
        size_t xi = ((size_t)b * L_SEQ + t) * D_DIM + col0 + wn + c8;
        s8v x = *(const s8v*)&XE[xi];
        s8v o;
#pragma unroll
        for (int u = 0; u < 4; ++u) {
            o[u]     = (short)f2bf(tanhf(bf2f((unsigned short)x[u])     + v0[u]));
            o[u + 4] = (short)f2bf(tanhf(bf2f((unsigned short)x[u + 4]) + v1[u]));
        }
        *(s8v*)&XE[xi] = o;
    }
}

// ---------------------------------------------------------------------------
// k_mlp_mfma: h = tanh(concat(XE[i],XE[j]) @ W1 + b1) fused with the rule-dot:
// partials[cb][m] = dot(h[m, 64-col-slice], Wt2[r_idx[m], slice]). No h store.
// 128x128 tile, K=2048.
// ---------------------------------------------------------------------------
__global__ __launch_bounds__(256) void k_mlp_mfma(
    const int* __restrict__ i_idx, const int* __restrict__ j_idx,
    const bf16_t* __restrict__ XE, const bf16_t* __restrict__ W1T,
    const float* __restrict__ b1, const bf16_t* __restrict__ Wt2,
    const int* __restrict__ r_idx, float* __restrict__ partials)
{
    __shared__ bf16_t As[128 * 32];            // 8 KB
    __shared__ bf16_t Bs[128 * 32];            // 8 KB

    const int tid = threadIdx.x;
    const int w = tid >> 6, l = tid & 63;
    const int q = l >> 4, t16 = l & 15;
    const int wm = (w >> 1) * 64, wn = (w & 1) * 64;
    const int row0 = blockIdx.x * 128, col0 = blockIdx.y * 128;

    const bf16_t* pi[2]; const bf16_t* pj[2];
#pragma unroll
    for (int r = 0; r < 2; ++r) {
        int m = row0 + (tid >> 2) + r * 64;
        pi[r] = XE + (size_t)i_idx[m] * D_DIM + ((tid & 3) << 3);
        pj[r] = XE + (size_t)j_idx[m] * D_DIM - D_DIM + ((tid & 3) << 3);  // k in [1024,2048)
    }
    const bf16_t* brow[2];
#pragma unroll
    for (int r = 0; r < 2; ++r)
        brow[r] = W1T + (size_t)(col0 + (tid >> 2) + r * 64) * (2 * D_DIM) + ((tid & 3) << 3);

    f4v acc[4][4];
#pragma unroll
    for (int i = 0; i < 4; ++i)
#pragma unroll
        for (int j = 0; j < 4; ++j) acc[i][j] = (f4v)0.f;

    for (int k0 = 0; k0 < 2 * D_DIM; k0 += 32) {
        s8v a0 = *(const s8v*)(((k0 < D_DIM) ? pi[0] : pj[0]) + k0);
        s8v a1 = *(const s8v*)(((k0 < D_DIM) ? pi[1] : pj[1]) + k0);
        s8v b0 = *(const s8v*)(brow[0] + k0);
        s8v b1v = *(const s8v*)(brow[1] + k0);
        __syncthreads();
        {
            int rr = (tid >> 2), cc = ((tid & 3) << 3);
            *(s8v*)&As[rr * 32 + cc]        = a0;
            *(s8v*)&As[(rr + 64) * 32 + cc] = a1;
            *(s8v*)&Bs[rr * 32 + cc]        = b0;
            *(s8v*)&Bs[(rr + 64) * 32 + cc] = b1v;
        }
        __syncthreads();
        s8v af[4], bfr[4];
#pragma unroll
        for (int ti = 0; ti < 4; ++ti)
            af[ti] = *(const s8v*)&As[(wm + ti * 16 + t16) * 32 + q * 8];
#pragma unroll
        for (int tj = 0; tj < 4; ++tj)
            bfr[tj] = *(const s8v*)&Bs[(wn + tj * 16 + t16) * 32 + q * 8];
#pragma unroll
        for (int ti = 0; ti < 4; ++ti)
#pragma unroll
            for (int tj = 0; tj < 4; ++tj)
                acc[ti][tj] = mfma16(af[ti], bfr[tj], acc[ti][tj]);
    }

    // fused epilogue in C-layout: tanh, dot with gathered rule row, 16-lane reduce
    const int cb = blockIdx.y * 2 + (w & 1);
#pragma unroll
    for (int ti = 0; ti < 4; ++ti) {
#pragma unroll
        for (int rg = 0; rg < 4; ++rg) {
            int m = row0 + wm + ti * 16 + q * 4 + rg;
            int r = r_idx[m];
            const bf16_t* wrow = Wt2 + (size_t)r * D_DIM + col0 + wn + t16;
            float pd = 0.f;
#pragma unroll
            for (int tj = 0; tj < 4; ++tj) {
                int col = col0 + wn + tj * 16 + t16;
                float h = tanhf(acc[ti][tj][rg] + b1[col]);
                pd += h * bf2f(wrow[tj * 16]);
            }
            pd += __shfl_xor(pd, 1);
            pd += __shfl_xor(pd, 2);
            pd += __shfl_xor(pd, 4);
            pd += __shfl_xor(pd, 8);
            if (t16 == 0)
                partials[(size_t)cb * M_NODES + m] = pd;
        }
    }
}

// ---------------------------------------------------------------------------
// k_reduce: out[m] = sum_cb partials[cb][m] + b2[r_idx[m]]   (deterministic)
// ---------------------------------------------------------------------------
__global__ __launch_bounds__(256) void k_reduce(
    const float* __restrict__ partials, const int* __restrict__ r_idx,
    const float* __restrict__ b2, float* __restrict__ out)
{
    int m = blockIdx.x * 256 + threadIdx.x;
    float s = 0.f;
#pragma unroll
    for (int cb = 0; cb < 16; ++cb)
        s += partials[(size_t)cb * M_NODES + m];
    out[m] = s + b2[r_idx[m]];
}

// ---------------------------------------------------------------------------
extern "C" void kernel_launch(void* const* d_in, const int* in_sizes, int n_in,
                              void* d_out, int out_size, void* d_ws, size_t ws_size,
                              hipStream_t stream) {
    const int*   tokens = (const int*)  d_in[0];
    const int*   i_idx  = (const int*)  d_in[1];
    const int*   j_idx  = (const int*)  d_in[2];
    const int*   r_idx  = (const int*)  d_in[3];
    const float* emb    = (const float*)d_in[4];
    const float* Wxh    = (const float*)d_in[5];
    const float* Whh    = (const float*)d_in[6];
    const float* bh     = (const float*)d_in[7];
    const float* h0     = (const float*)d_in[8];
    const float* W1     = (const float*)d_in[9];
    const float* b1     = (const float*)d_in[10];
    const float* W2     = (const float*)d_in[11];
    const float* b2     = (const float*)d_in[12];
    float* out = (float*)d_out;

    // Workspace (156 MiB total; R2 proved >=172 MiB is safe):
    bf16_t* XE   = (bf16_t*)d_ws;                        // [B*L][D]  128 MiB
    bf16_t* WxhT = XE   + (size_t)M_NODES * D_DIM;       // [D][D]      2 MiB
    bf16_t* WhhT = WxhT + (size_t)D_DIM * D_DIM;         // [D][D]      2 MiB
    bf16_t* W1T  = WhhT + (size_t)D_DIM * D_DIM;         // [D][2D]     4 MiB
    bf16_t* Wt2  = W1T  + (size_t)2 * D_DIM * D_DIM;     // [R][D]     16 MiB
    bf16_t* h0b  = Wt2  + (size_t)R_RULES * D_DIM;       // [D] (pad 2048)
    float*  par  = (float*)(h0b + 2048);                 // [16][M]     4 MiB

    // weight conversions (one-time per launch, independent)
    k_transcvt<<<dim3(D_DIM / 32, D_DIM / 32), dim3(32, 8), 0, stream>>>(Wxh, WxhT, D_DIM, D_DIM);
    k_transcvt<<<dim3(D_DIM / 32, D_DIM / 32), dim3(32, 8), 0, stream>>>(Whh, WhhT, D_DIM, D_DIM);
    k_transcvt<<<dim3(D_DIM / 32, 2 * D_DIM / 32), dim3(32, 8), 0, stream>>>(W1, W1T, 2 * D_DIM, D_DIM);
    k_transcvt<<<dim3(R_RULES / 32, D_DIM / 32), dim3(32, 8), 0, stream>>>(W2, Wt2, D_DIM, R_RULES);
    k_cvt_h0<<<1, 256, 0, stream>>>(h0, h0b);

    // 1) XE = bf16(emb[tokens] @ Wxh + bh)
    k_xw_mfma<<<dim3(M_NODES / 128, D_DIM / 128), 256, 0, stream>>>(tokens, emb, WxhT, bh, XE);

    // 2) 64 sequential RNN steps (in-place on XE)
    for (int t = 0; t < L_SEQ; ++t) {
        const bf16_t* Abase = (t == 0) ? h0b : (XE + (size_t)(t - 1) * D_DIM);
        int strideRow       = (t == 0) ? 0   : L_SEQ * D_DIM;
        k_step_mfma<<<dim3(B_BATCH / 64, D_DIM / 64), 256, 0, stream>>>(
            Abase, strideRow, WhhT, XE, t);
    }

    // 3) MLP + fused rule-dot partials
    k_mlp_mfma<<<dim3(M_NODES / 128, D_DIM / 128), 256, 0, stream>>>(
        i_idx, j_idx, XE, W1T, b1, Wt2, r_idx, par);

    // 4) deterministic reduce + b2
    k_reduce<<<M_NODES / 256, 256, 0, stream>>>(par, r_idx, b2, out);
}

// Round 7
// 1345.554 us; speedup vs baseline: 6.7807x; 1.2330x over previous
//
#include <hip/hip_runtime.h>

// V=10000, R=8192, D=1024, B=1024, L=64, M=65536
// R7: R6 (1659 us, absmax 7.8e-3) + (a) SW-prefetch K-loops, (b) k_step 512
// threads (2 waves/SIMD TLP) + barrier-free per-wave epilogues, (c) fast_tanh
// via __expf+rcp, (d) emb pre-converted to bf16 (k_xw A-path = pure bf16).
#define D_DIM   1024
#define L_SEQ   64
#define B_BATCH 1024
#define M_NODES 65536
#define R_RULES 8192
#define V_VOCAB 10000

typedef unsigned short bf16_t;
typedef __attribute__((ext_vector_type(8))) short s8v;   // 8 bf16 (MFMA A/B frag)
typedef __attribute__((ext_vector_type(4))) short s4v;   // 4 bf16
typedef __attribute__((ext_vector_type(4))) float f4v;   // MFMA C/D frag

static __device__ __forceinline__ float bf2f(unsigned short u) {
    union { unsigned int i; float f; } v; v.i = ((unsigned int)u) << 16; return v.f;
}
static __device__ __forceinline__ unsigned short f2bf(float f) {  // RNE
    union { float f; unsigned int i; } v; v.f = f;
    return (unsigned short)((v.i + 0x7FFFu + ((v.i >> 16) & 1u)) >> 16);
}
// tanh(x) = (e^2x - 1)/(e^2x + 1); clamp keeps e^2x finite. ~8 VALU ops vs ~20
// for libm tanhf. rel err ~1e-6 << bf16 rounding already in the pipeline.
static __device__ __forceinline__ float fast_tanh(float x) {
    float xc = fminf(fmaxf(x, -15.f), 15.f);
    float t  = __expf(2.f * xc);
    return (t - 1.f) * __builtin_amdgcn_rcpf(t + 1.f);
}

static __device__ __forceinline__ f4v mfma16(s8v a, s8v b, f4v c) {
    return __builtin_amdgcn_mfma_f32_16x16x32_bf16(a, b, c, 0, 0, 0);
}

// ---------------------------------------------------------------------------
// k_cvt_emb: embB = bf16(emb)   (V*D = 10,240,000 elems; 8/thread; 5000 blocks)
// ---------------------------------------------------------------------------
__global__ __launch_bounds__(256) void k_cvt_emb(
    const float* __restrict__ emb, bf16_t* __restrict__ embB)
{
    size_t i = ((size_t)blockIdx.x * 256 + threadIdx.x) * 8;
    f4v x0 = *(const f4v*)&emb[i];
    f4v x1 = *(const f4v*)&emb[i + 4];
    s8v o;
    o[0] = (short)f2bf(x0.x); o[1] = (short)f2bf(x0.y);
    o[2] = (short)f2bf(x0.z); o[3] = (short)f2bf(x0.w);
    o[4] = (short)f2bf(x1.x); o[5] = (short)f2bf(x1.y);
    o[6] = (short)f2bf(x1.z); o[7] = (short)f2bf(x1.w);
    *(s8v*)&embB[i] = o;
}

// ---------------------------------------------------------------------------
// k_transcvt: dst[n][k] = bf16(src[k][n])   (weights -> B-operand layout)
// ---------------------------------------------------------------------------
__global__ __launch_bounds__(256) void k_transcvt(
    const float* __restrict__ src, bf16_t* __restrict__ dst, int K, int N)
{
    __shared__ float s[32][33];
    int n0 = blockIdx.x * 32, k0 = blockIdx.y * 32;
    int tx = threadIdx.x, ty = threadIdx.y;  // (32,8)
#pragma unroll
    for (int i = 0; i < 4; ++i)
        s[ty + i * 8][tx] = src[(size_t)(k0 + ty + i * 8) * N + n0 + tx];
    __syncthreads();
#pragma unroll
    for (int i = 0; i < 4; ++i)
        dst[(size_t)(n0 + ty + i * 8) * K + k0 + tx] = f2bf(s[tx][ty + i * 8]);
}

__global__ __launch_bounds__(256) void k_cvt_h0(
    const float* __restrict__ h0, bf16_t* __restrict__ h0b)
{
    for (int u = threadIdx.x; u < D_DIM; u += 256) h0b[u] = f2bf(h0[u]);
}

// ---------------------------------------------------------------------------
// k_xw_mfma: XE[n,:] = bf16(embB[tokens[n],:] @ Wxh + bh)
// 128x128 tile, BK=32, bf16 A gather + SW-prefetch staging.
// ---------------------------------------------------------------------------
__global__ __launch_bounds__(256) void k_xw_mfma(
    const int* __restrict__ tokens, const bf16_t* __restrict__ embB,
    const bf16_t* __restrict__ WxhT, const float* __restrict__ bh,
    bf16_t* __restrict__ XE)
{
    __shared__ bf16_t As[128 * 32];            // 8 KB
    __shared__ bf16_t Bs[128 * 32];            // 8 KB
    __shared__ float  epi[4][16][68];          // 17.4 KB (per-wave private)

    const int tid = threadIdx.x;
    const int w = tid >> 6, l = tid & 63;
    const int q = l >> 4, t16 = l & 15;
    const int wm = (w >> 1) * 64, wn = (w & 1) * 64;
    const int row0 = blockIdx.x * 128, col0 = blockIdx.y * 128;

    const bf16_t* arow[2];
#pragma unroll
    for (int r = 0; r < 2; ++r)
        arow[r] = embB + (size_t)tokens[row0 + (tid >> 2) + r * 64] * D_DIM + ((tid & 3) << 3);
    const bf16_t* brow[2];
#pragma unroll
    for (int r = 0; r < 2; ++r)
        brow[r] = WxhT + (size_t)(col0 + (tid >> 2) + r * 64) * D_DIM + ((tid & 3) << 3);

    f4v acc[4][4];
#pragma unroll
    for (int i = 0; i < 4; ++i)
#pragma unroll
        for (int j = 0; j < 4; ++j) acc[i][j] = (f4v)0.f;

    // prefetch k=0
    s8v a0 = *(const s8v*)(arow[0]);
    s8v a1 = *(const s8v*)(arow[1]);
    s8v b0 = *(const s8v*)(brow[0]);
    s8v b1 = *(const s8v*)(brow[1]);

    const int rr = tid >> 2, cc = (tid & 3) << 3;
    for (int k0 = 0; k0 < D_DIM; k0 += 32) {
        __syncthreads();                       // prev iter frag reads done
        *(s8v*)&As[rr * 32 + cc]        = a0;
        *(s8v*)&As[(rr + 64) * 32 + cc] = a1;
        *(s8v*)&Bs[rr * 32 + cc]        = b0;
        *(s8v*)&Bs[(rr + 64) * 32 + cc] = b1;
        int kn = k0 + 32;
        if (kn < D_DIM) {                      // issue next loads early
            a0 = *(const s8v*)(arow[0] + kn);
            a1 = *(const s8v*)(arow[1] + kn);
            b0 = *(const s8v*)(brow[0] + kn);
            b1 = *(const s8v*)(brow[1] + kn);
        }
        __syncthreads();
        s8v af[4], bfr[4];
#pragma unroll
        for (int ti = 0; ti < 4; ++ti)
            af[ti] = *(const s8v*)&As[(wm + ti * 16 + t16) * 32 + q * 8];
#pragma unroll
        for (int tj = 0; tj < 4; ++tj)
            bfr[tj] = *(const s8v*)&Bs[(wn + tj * 16 + t16) * 32 + q * 8];
#pragma unroll
        for (int ti = 0; ti < 4; ++ti)
#pragma unroll
            for (int tj = 0; tj < 4; ++tj)
                acc[ti][tj] = mfma16(af[ti], bfr[tj], acc[ti][tj]);
    }

    // epilogue: +bias, bf16, per-wave LDS transpose (no barriers: epi[w] is
    // wave-private and waves execute LDS ops in order)
    const int lr = l >> 2, c16 = (l & 3) * 16;
    f4v bias[4];
#pragma unroll
    for (int u = 0; u < 4; ++u)
        bias[u] = *(const f4v*)&bh[col0 + wn + c16 + u * 4];
#pragma unroll
    for (int ti = 0; ti < 4; ++ti) {
#pragma unroll
        for (int tj = 0; tj < 4; ++tj)
#pragma unroll
            for (int rg = 0; rg < 4; ++rg)
                epi[w][q * 4 + rg][tj * 16 + t16] = acc[ti][tj][rg];
        s8v o0, o1;
#pragma unroll
        for (int u = 0; u < 8; ++u) {
            o0[u] = (short)f2bf(epi[w][lr][c16 + u]     + bias[u >> 2][u & 3]);
            o1[u] = (short)f2bf(epi[w][lr][c16 + 8 + u] + bias[2 + (u >> 2)][u & 3]);
        }
        size_t orow = (size_t)(row0 + wm + ti * 16 + lr) * D_DIM + col0 + wn + c16;
        *(s8v*)&XE[orow]     = o0;
        *(s8v*)&XE[orow + 8] = o1;
    }
}

// ---------------------------------------------------------------------------
// k_step_mfma (x64): y = tanh(XE[b*L+t,:] + h_prev[b,:] @ Whh); XE[b*L+t,:] = bf16(y)
// 64x64 tile, 512 threads (8 waves = 2/SIMD for TLP), SW-prefetch, fast_tanh.
// Wave (wr,wc) = (w>>2, w&3) computes rows wr*32+[0,32) x cols wc*16+[0,16).
// ---------------------------------------------------------------------------
__global__ __launch_bounds__(512) void k_step_mfma(
    const bf16_t* __restrict__ Abase, int strideRow,
    const bf16_t* __restrict__ WhhT, bf16_t* __restrict__ XE, int t)
{
    __shared__ bf16_t As[64 * 32];             // 4 KB
    __shared__ bf16_t Bs[64 * 32];             // 4 KB
    __shared__ float  epi[8][16][20];          // 10.2 KB (per-wave private)

    const int tid = threadIdx.x;
    const int w = tid >> 6, l = tid & 63;
    const int q = l >> 4, t16 = l & 15;
    const int wr = w >> 2, wc = w & 3;
    const int row0 = blockIdx.x * 64, col0 = blockIdx.y * 64;

    const bf16_t* asrc = Abase + (size_t)(row0 + (tid >> 3)) * strideRow + ((tid & 7) << 2);
    const bf16_t* bsrc = WhhT + (size_t)(col0 + (tid >> 3)) * D_DIM + ((tid & 7) << 2);

    f4v acc[2];
    acc[0] = (f4v)0.f; acc[1] = (f4v)0.f;

    s4v rA = *(const s4v*)(asrc);
    s4v rB = *(const s4v*)(bsrc);

    const int srow = tid >> 3, scol = (tid & 7) << 2;
    for (int k0 = 0; k0 < D_DIM; k0 += 32) {
        __syncthreads();
        *(s4v*)&As[srow * 32 + scol] = rA;
        *(s4v*)&Bs[srow * 32 + scol] = rB;
        int kn = k0 + 32;
        if (kn < D_DIM) {
            rA = *(const s4v*)(asrc + kn);
            rB = *(const s4v*)(bsrc + kn);
        }
        __syncthreads();
        s8v af[2], bfr;
#pragma unroll
        for (int ti = 0; ti < 2; ++ti)
            af[ti] = *(const s8v*)&As[(wr * 32 + ti * 16 + t16) * 32 + q * 8];
        bfr = *(const s8v*)&Bs[(wc * 16 + t16) * 32 + q * 8];
#pragma unroll
        for (int ti = 0; ti < 2; ++ti)
            acc[ti] = mfma16(af[ti], bfr, acc[ti]);
    }

    // per-wave epilogue, no barriers
    const int lr = l >> 2, c4 = (l & 3) * 4;
#pragma unroll
    for (int ti = 0; ti < 2; ++ti) {
#pragma unroll
        for (int rg = 0; rg < 4; ++rg)
            epi[w][q * 4 + rg][t16] = acc[ti][rg];
        f4v v = *(const f4v*)&epi[w][lr][c4];
        int b = row0 + wr * 32 + ti * 16 + lr;
        size_t xi = ((size_t)b * L_SEQ + t) * D_DIM + col0 + wc * 16 + c4;
        s4v x = *(const s4v*)&XE[xi];
        s4v o;
#pragma unroll
        for (int u = 0; u < 4; ++u)
            o[u] = (short)f2bf(fast_tanh(bf2f((unsigned short)x[u]) + v[u]));
        *(s4v*)&XE[xi] = o;
    }
}

// ---------------------------------------------------------------------------
// k_mlp_mfma: h = tanh(concat(XE[i],XE[j]) @ W1 + b1) fused with rule-dot:
// partials[cb][m] = dot(h[m, 64-col-slice], Wt2[r_idx[m], slice]). No h store.
// 128x128 tile, K=2048, SW-prefetch, fast_tanh.
// ---------------------------------------------------------------------------
__global__ __launch_bounds__(256) void k_mlp_mfma(
    const int* __restrict__ i_idx, const int* __restrict__ j_idx,
    const bf16_t* __restrict__ XE, const bf16_t* __restrict__ W1T,
    const float* __restrict__ b1, const bf16_t* __restrict__ Wt2,
    const int* __restrict__ r_idx, float* __restrict__ partials)
{
    __shared__ bf16_t As[128 * 32];            // 8 KB
    __shared__ bf16_t Bs[128 * 32];            // 8 KB

    const int tid = threadIdx.x;
    const int w = tid >> 6, l = tid & 63;
    const int q = l >> 4, t16 = l & 15;
    const int wm = (w >> 1) * 64, wn = (w & 1) * 64;
    const int row0 = blockIdx.x * 128, col0 = blockIdx.y * 128;

    const bf16_t* pi[2]; const bf16_t* pj[2];
#pragma unroll
    for (int r = 0; r < 2; ++r) {
        int m = row0 + (tid >> 2) + r * 64;
        pi[r] = XE + (size_t)i_idx[m] * D_DIM + ((tid & 3) << 3);
        pj[r] = XE + (size_t)j_idx[m] * D_DIM - D_DIM + ((tid & 3) << 3);  // k in [1024,2048)
    }
    const bf16_t* brow[2];
#pragma unroll
    for (int r = 0; r < 2; ++r)
        brow[r] = W1T + (size_t)(col0 + (tid >> 2) + r * 64) * (2 * D_DIM) + ((tid & 3) << 3);

    f4v acc[4][4];
#pragma unroll
    for (int i = 0; i < 4; ++i)
#pragma unroll
        for (int j = 0; j < 4; ++j) acc[i][j] = (f4v)0.f;

    // prefetch k=0
    s8v a0 = *(const s8v*)(pi[0]);
    s8v a1 = *(const s8v*)(pi[1]);
    s8v b0 = *(const s8v*)(brow[0]);
    s8v b1v = *(const s8v*)(brow[1]);

    const int rr = tid >> 2, cc = (tid & 3) << 3;
    for (int k0 = 0; k0 < 2 * D_DIM; k0 += 32) {
        __syncthreads();
        *(s8v*)&As[rr * 32 + cc]        = a0;
        *(s8v*)&As[(rr + 64) * 32 + cc] = a1;
        *(s8v*)&Bs[rr * 32 + cc]        = b0;
        *(s8v*)&Bs[(rr + 64) * 32 + cc] = b1v;
        int kn = k0 + 32;
        if (kn < 2 * D_DIM) {
            a0  = *(const s8v*)(((kn < D_DIM) ? pi[0] : pj[0]) + kn);
            a1  = *(const s8v*)(((kn < D_DIM) ? pi[1] : pj[1]) + kn);
            b0  = *(const s8v*)(brow[0] + kn);
            b1v = *(const s8v*)(brow[1] + kn);
        }
        __syncthreads();
        s8v af[4], bfr[4];
#pragma unroll
        for (int ti = 0; ti < 4; ++ti)
            af[ti] = *(const s8v*)&As[(wm + ti * 16 + t16) * 32 + q * 8];
#pragma unroll
        for (int tj = 0; tj < 4; ++tj)
            bfr[tj] = *(const s8v*)&Bs[(wn + tj * 16 + t16) * 32 + q * 8];
#pragma unroll
        for (int ti = 0; ti < 4; ++ti)
#pragma unroll
            for (int tj = 0; tj < 4; ++tj)
                acc[ti][tj] = mfma16(af[ti], bfr[tj], acc[ti][tj]);
    }

    // fused epilogue in C-layout: fast_tanh, dot with gathered rule row, 16-lane reduce
    const int cb = blockIdx.y * 2 + (w & 1);
#pragma unroll
    for (int ti = 0; ti < 4; ++ti) {
#pragma unroll
        for (int rg = 0; rg < 4; ++rg) {
            int m = row0 + wm + ti * 16 + q * 4 + rg;
            int r = r_idx[m];
            const bf16_t* wrow = Wt2 + (size_t)r * D_DIM + col0 + wn + t16;
            float pd = 0.f;
#pragma unroll
            for (int tj = 0; tj < 4; ++tj) {
                int col = col0 + wn + tj * 16 + t16;
                float h = fast_tanh(acc[ti][tj][rg] + b1[col]);
                pd += h * bf2f(wrow[tj * 16]);
            }
            pd += __shfl_xor(pd, 1);
            pd += __shfl_xor(pd, 2);
            pd += __shfl_xor(pd, 4);
            pd += __shfl_xor(pd, 8);
            if (t16 == 0)
                partials[(size_t)cb * M_NODES + m] = pd;
        }
    }
}

// ---------------------------------------------------------------------------
// k_reduce: out[m] = sum_cb partials[cb][m] + b2[r_idx[m]]   (deterministic)
// ---------------------------------------------------------------------------
__global__ __launch_bounds__(256) void k_reduce(
    const float* __restrict__ partials, const int* __restrict__ r_idx,
    const float* __restrict__ b2, float* __restrict__ out)
{
    int m = blockIdx.x * 256 + threadIdx.x;
    float s = 0.f;
#pragma unroll
    for (int cb = 0; cb < 16; ++cb)
        s += partials[(size_t)cb * M_NODES + m];
    out[m] = s + b2[r_idx[m]];
}

// ---------------------------------------------------------------------------
extern "C" void kernel_launch(void* const* d_in, const int* in_sizes, int n_in,
                              void* d_out, int out_size, void* d_ws, size_t ws_size,
                              hipStream_t stream) {
    const int*   tokens = (const int*)  d_in[0];
    const int*   i_idx  = (const int*)  d_in[1];
    const int*   j_idx  = (const int*)  d_in[2];
    const int*   r_idx  = (const int*)  d_in[3];
    const float* emb    = (const float*)d_in[4];
    const float* Wxh    = (const float*)d_in[5];
    const float* Whh    = (const float*)d_in[6];
    const float* bh     = (const float*)d_in[7];
    const float* h0     = (const float*)d_in[8];
    const float* W1     = (const float*)d_in[9];
    const float* b1     = (const float*)d_in[10];
    const float* W2     = (const float*)d_in[11];
    const float* b2     = (const float*)d_in[12];
    float* out = (float*)d_out;

    // Workspace (~156 MiB, same footprint as the passing R6).
    // embB (20 MiB) ALIASES the WhhT/W1T/Wt2 region (22 MiB): embB is dead
    // after k_xw_mfma; those conversions run after it (stream-ordered).
    bf16_t* XE   = (bf16_t*)d_ws;                        // [B*L][D]  128 MiB
    bf16_t* WxhT = XE   + (size_t)M_NODES * D_DIM;       // [D][D]      2 MiB
    bf16_t* WhhT = WxhT + (size_t)D_DIM * D_DIM;         // [D][D]      2 MiB
    bf16_t* W1T  = WhhT + (size_t)D_DIM * D_DIM;         // [D][2D]     4 MiB
    bf16_t* Wt2  = W1T  + (size_t)2 * D_DIM * D_DIM;     // [R][D]     16 MiB
    bf16_t* embB = WhhT;                                 // [V][D]     20 MiB (alias)
    bf16_t* h0b  = Wt2  + (size_t)R_RULES * D_DIM;       // [D] (pad 2048)
    float*  par  = (float*)(h0b + 2048);                 // [16][M]     4 MiB

    // Phase 1: emb->bf16, Wxh, h0 (needed by k_xw / k_step)
    k_cvt_emb<<<V_VOCAB * D_DIM / 2048, 256, 0, stream>>>(emb, embB);
    k_transcvt<<<dim3(D_DIM / 32, D_DIM / 32), dim3(32, 8), 0, stream>>>(Wxh, WxhT, D_DIM, D_DIM);
    k_cvt_h0<<<1, 256, 0, stream>>>(h0, h0b);

    // Phase 2: XE = bf16(embB[tokens] @ Wxh + bh)   (last reader of embB)
    k_xw_mfma<<<dim3(M_NODES / 128, D_DIM / 128), 256, 0, stream>>>(tokens, embB, WxhT, bh, XE);

    // Phase 3: remaining weight conversions (overwrite embB region)
    k_transcvt<<<dim3(D_DIM / 32, D_DIM / 32), dim3(32, 8), 0, stream>>>(Whh, WhhT, D_DIM, D_DIM);
    k_transcvt<<<dim3(D_DIM / 32, 2 * D_DIM / 32), dim3(32, 8), 0, stream>>>(W1, W1T, 2 * D_DIM, D_DIM);
    k_transcvt<<<dim3(R_RULES / 32, D_DIM / 32), dim3(32, 8), 0, stream>>>(W2, Wt2, D_DIM, R_RULES);

    // Phase 4: 64 sequential RNN steps (in-place on XE)
    for (int t = 0; t < L_SEQ; ++t) {
        const bf16_t* Abase = (t == 0) ? h0b : (XE + (size_t)(t - 1) * D_DIM);
        int strideRow       = (t == 0) ? 0   : L_SEQ * D_DIM;
        k_step_mfma<<<dim3(B_BATCH / 64, D_DIM / 64), 512, 0, stream>>>(
            Abase, strideRow, WhhT, XE, t);
    }

    // Phase 5: MLP + fused rule-dot partials
    k_mlp_mfma<<<dim3(M_NODES / 128, D_DIM / 128), 256, 0, stream>>>(
        i_idx, j_idx, XE, W1T, b1, Wt2, r_idx, par);

    // Phase 6: deterministic reduce + b2
    k_reduce<<<M_NODES / 256, 256, 0, stream>>>(par, r_idx, b2, out);
}